// Round 1
// baseline (832.294 us; speedup 1.0000x reference)
//
#include <hip/hip_runtime.h>
#include <math.h>

// ---------------------------------------------------------------------------
// PPFNet pipeline on MI355X.
// B=16 clouds x 2048 pts, K=16 knn, all f32.
//  K1 knn_partial : thread = (point, parity-half); exact top-16 of 1024 cands
//  K2 knn_merge   : merge 2 halves -> nbr[N][16]; also computes ppf[N][16][4]
//  K3 conv1       : 8 threads/node (2 edges each), MLP(4->32->32), max, relu
//  K4a gfromh     : G = h @ W2a[0:32] + b2a   (per-node GEMM, hoists conv2 L1)
//  K4b conv2      : per-edge: relu(G[j] + ppf@W2a[32:36]) -> 32x32 -> max,relu
//  K5 pool_fc     : per-cloud max pool + Linear(32,40)
// Weights are read with wave-uniform indices -> scalar loads (no LDS needed).
// Activations in statically-indexed registers (all reduction loops unrolled).
// ---------------------------------------------------------------------------

#define NPER 2048
#define NCLOUD 16
#define NPTS (NPER * NCLOUD)
#define KNN 16

// ws layout (bytes). pd/pi die after K2; their space is reused for h/G.
#define OFF_PD   (size_t)(0u)          // float [N][2][16]  (4 MB)
#define OFF_PI   (size_t)(4u << 20)    // int   [N][2][16]  (4 MB)
#define OFF_NBR  (size_t)(8u << 20)    // int   [N][16]     (2 MB)
#define OFF_PPF  (size_t)(10u << 20)   // float [N][16][4]  (8 MB)
#define OFF_H    (size_t)(0u)          // float [N][32]     (reuses PD)
#define OFF_G    (size_t)(4u << 20)    // float [N][32]     (reuses PI)
#define OFF_H2   (size_t)(18u << 20)   // float [N][32]     (4 MB) -> 22 MB total

// ---------------------------------------------------------------------------
// K1: exact top-16 among this thread's parity-half of the cloud's candidates.
// Sorted insertion list via fully-unrolled cmov chain (no dynamic reg index).
// d2 uses non-contracted mul/add to match the numpy reference bit pattern.
// ---------------------------------------------------------------------------
__global__ __launch_bounds__(256) void knn_partial(const float* __restrict__ pos,
                                                   float* __restrict__ pd,
                                                   int* __restrict__ piw) {
    const int cloud = blockIdx.x >> 4;           // 16 blocks per cloud
    const int prow  = (blockIdx.x & 15) * 128;   // 128 points per block
    const int tid   = threadIdx.x;
    const int lp    = prow + (tid >> 1);         // local point idx 0..2047
    const int half  = tid & 1;                   // candidate parity
    const int g     = cloud * NPER + lp;

    const float px = pos[g * 3 + 0];
    const float py = pos[g * 3 + 1];
    const float pz = pos[g * 3 + 2];

    float dl[16];
    int   il[16];
#pragma unroll
    for (int m = 0; m < 16; ++m) { dl[m] = INFINITY; il[m] = -1; }

    __shared__ float tile[768];  // 256 points * xyz, packed (2-way bank alias = free)

    for (int t = 0; t < 8; ++t) {
        __syncthreads();
        const int tb = cloud * NPER * 3 + t * 768;
        tile[tid]       = pos[tb + tid];
        tile[tid + 256] = pos[tb + tid + 256];
        tile[tid + 512] = pos[tb + tid + 512];
        __syncthreads();
#pragma unroll 2
        for (int jj = 0; jj < 128; ++jj) {
            const int cl = 2 * jj + half;
            const float cx = tile[3 * cl + 0];
            const float cy = tile[3 * cl + 1];
            const float cz = tile[3 * cl + 2];
            const float dx = __fsub_rn(px, cx);
            const float dy = __fsub_rn(py, cy);
            const float dz = __fsub_rn(pz, cz);
            const float d2 = __fadd_rn(__fadd_rn(__fmul_rn(dx, dx), __fmul_rn(dy, dy)),
                                       __fmul_rn(dz, dz));
            const int cand = t * 256 + cl;
            if (cand != lp && d2 < dl[15]) {
#pragma unroll
                for (int m = 15; m > 0; --m) {
                    const bool up   = d2 < dl[m - 1];
                    const bool here = d2 < dl[m];
                    dl[m] = up ? dl[m - 1] : (here ? d2 : dl[m]);
                    il[m] = up ? il[m - 1] : (here ? cand : il[m]);
                }
                if (d2 < dl[0]) { dl[0] = d2; il[0] = cand; }
            }
        }
    }

    float* po = pd  + ((size_t)g * 2 + half) * 16;
    int*   qo = piw + ((size_t)g * 2 + half) * 16;
#pragma unroll
    for (int m = 0; m < 16; ++m) { po[m] = dl[m]; qo[m] = il[m]; }
}

// ---------------------------------------------------------------------------
// K2: merge the two 16-lists per point -> nbr (global idx), then compute PPF.
// ---------------------------------------------------------------------------
__device__ __forceinline__ float angf(float ax, float ay, float az,
                                      float bx, float by, float bz) {
    const float cx = ay * bz - az * by;
    const float cy = az * bx - ax * bz;
    const float cz = ax * by - ay * bx;
    const float cn = sqrtf(cx * cx + cy * cy + cz * cz);
    const float dt = ax * bx + ay * by + az * bz;
    return atan2f(cn, dt);
}

__global__ __launch_bounds__(256) void knn_merge_ppf(const float* __restrict__ pos,
                                                     const float* __restrict__ nrm,
                                                     const float* __restrict__ pd,
                                                     const int* __restrict__ piw,
                                                     int* __restrict__ nbr,
                                                     float* __restrict__ ppf) {
    const int g = blockIdx.x * 256 + threadIdx.x;
    const int cloud = g >> 11;

    float dl[16];
    int   il[16];
#pragma unroll
    for (int m = 0; m < 16; ++m) { dl[m] = INFINITY; il[m] = -1; }

    const float* ps = pd  + (size_t)g * 32;
    const int*   is = piw + (size_t)g * 32;
#pragma unroll
    for (int s = 0; s < 32; ++s) {
        const float d2 = ps[s];
        const int cand = is[s];
        if (d2 < dl[15]) {
#pragma unroll
            for (int m = 15; m > 0; --m) {
                const bool up   = d2 < dl[m - 1];
                const bool here = d2 < dl[m];
                dl[m] = up ? dl[m - 1] : (here ? d2 : dl[m]);
                il[m] = up ? il[m - 1] : (here ? cand : il[m]);
            }
            if (d2 < dl[0]) { dl[0] = d2; il[0] = cand; }
        }
    }

    const int base = cloud * NPER;
    const float pix = pos[g * 3 + 0], piy = pos[g * 3 + 1], piz = pos[g * 3 + 2];
    const float nix = nrm[g * 3 + 0], niy = nrm[g * 3 + 1], niz = nrm[g * 3 + 2];

#pragma unroll
    for (int m = 0; m < 16; ++m) {
        const int j = base + il[m];
        nbr[g * 16 + m] = j;
        const float pjx = pos[j * 3 + 0], pjy = pos[j * 3 + 1], pjz = pos[j * 3 + 2];
        const float njx = nrm[j * 3 + 0], njy = nrm[j * 3 + 1], njz = nrm[j * 3 + 2];
        const float dx = pjx - pix, dy = pjy - piy, dz = pjz - piz;
        float4 v;
        v.x = sqrtf(dx * dx + dy * dy + dz * dz);
        v.y = angf(nix, niy, niz, dx, dy, dz);
        v.z = angf(njx, njy, njz, dx, dy, dz);
        v.w = angf(nix, niy, niz, njx, njy, njz);
        ((float4*)ppf)[(size_t)g * 16 + m] = v;
    }
}

// ---------------------------------------------------------------------------
// K3: conv1. 8 threads/node, 2 edges each. MLP(4->32)->relu->(32->32),
// max over edges (within thread, then shfl_xor across the 8-lane group), relu.
// ---------------------------------------------------------------------------
__global__ __launch_bounds__(256) void conv1_kernel(const float* __restrict__ ppf,
                                                    const float* __restrict__ W1a,
                                                    const float* __restrict__ b1a,
                                                    const float* __restrict__ W1b,
                                                    const float* __restrict__ b1b,
                                                    float* __restrict__ h) {
    const int gid  = blockIdx.x * 256 + threadIdx.x;
    const int node = gid >> 3;
    const int sub  = gid & 7;

    const float4 x0 = ((const float4*)ppf)[(size_t)node * 16 + sub * 2 + 0];
    const float4 x1 = ((const float4*)ppf)[(size_t)node * 16 + sub * 2 + 1];

    float h1[2][32];
#pragma unroll
    for (int o = 0; o < 32; ++o) {
        const float w0 = W1a[o], w1 = W1a[32 + o], w2 = W1a[64 + o], w3 = W1a[96 + o];
        const float b = b1a[o];
        h1[0][o] = fmaxf(b + x0.x * w0 + x0.y * w1 + x0.z * w2 + x0.w * w3, 0.f);
        h1[1][o] = fmaxf(b + x1.x * w0 + x1.y * w1 + x1.z * w2 + x1.w * w3, 0.f);
    }

#pragma unroll 1
    for (int ob = 0; ob < 4; ++ob) {
        float a0[8], a1[8];
#pragma unroll
        for (int u = 0; u < 8; ++u) { const float b = b1b[ob * 8 + u]; a0[u] = b; a1[u] = b; }
#pragma unroll
        for (int hh = 0; hh < 32; ++hh) {
            const float h0v = h1[0][hh], h1v = h1[1][hh];
#pragma unroll
            for (int u = 0; u < 8; ++u) {
                const float w = W1b[hh * 32 + ob * 8 + u];
                a0[u] += h0v * w;
                a1[u] += h1v * w;
            }
        }
#pragma unroll
        for (int u = 0; u < 8; ++u) {
            float v = fmaxf(a0[u], a1[u]);
            v = fmaxf(v, __shfl_xor(v, 1));
            v = fmaxf(v, __shfl_xor(v, 2));
            v = fmaxf(v, __shfl_xor(v, 4));
            if (sub == 0) h[(size_t)node * 32 + ob * 8 + u] = fmaxf(v, 0.f);
        }
    }
}

// ---------------------------------------------------------------------------
// K4a: G = h @ W2a[0:32,:] + b2a  (per node) -- hoists conv2's input layer
// out of the edge loop (16x less work than per-edge).
// ---------------------------------------------------------------------------
__global__ __launch_bounds__(256) void gfromh(const float* __restrict__ h,
                                              const float* __restrict__ W2a,
                                              const float* __restrict__ b2a,
                                              float* __restrict__ G) {
    const int n = blockIdx.x * 256 + threadIdx.x;
    float hr[32];
    const float4* row = (const float4*)(h + (size_t)n * 32);
#pragma unroll
    for (int q = 0; q < 8; ++q) {
        const float4 v = row[q];
        hr[q * 4 + 0] = v.x; hr[q * 4 + 1] = v.y; hr[q * 4 + 2] = v.z; hr[q * 4 + 3] = v.w;
    }
    float acc[32];
#pragma unroll
    for (int o = 0; o < 32; ++o) acc[o] = b2a[o];
#pragma unroll
    for (int c = 0; c < 32; ++c) {
        const float hv = hr[c];
#pragma unroll
        for (int o = 0; o < 32; ++o) acc[o] += hv * W2a[c * 32 + o];
    }
    float4* go = (float4*)(G + (size_t)n * 32);
#pragma unroll
    for (int q = 0; q < 8; ++q) {
        float4 v;
        v.x = acc[q * 4 + 0]; v.y = acc[q * 4 + 1]; v.z = acc[q * 4 + 2]; v.w = acc[q * 4 + 3];
        go[q] = v;
    }
}

// ---------------------------------------------------------------------------
// K4b: conv2 per-edge part: h1 = relu(G[j] + ppf @ W2a[32:36,:]), then 32x32
// output layer, max over edges, relu.
// ---------------------------------------------------------------------------
__global__ __launch_bounds__(256) void conv2_kernel(const float* __restrict__ ppf,
                                                    const int* __restrict__ nbr,
                                                    const float* __restrict__ G,
                                                    const float* __restrict__ W2a,
                                                    const float* __restrict__ W2b,
                                                    const float* __restrict__ b2b,
                                                    float* __restrict__ h2) {
    const int gid  = blockIdx.x * 256 + threadIdx.x;
    const int node = gid >> 3;
    const int sub  = gid & 7;

    const int j0 = nbr[node * 16 + sub * 2 + 0];
    const int j1 = nbr[node * 16 + sub * 2 + 1];

    float h1[2][32];
    {
        const float4* r0 = (const float4*)(G + (size_t)j0 * 32);
        const float4* r1 = (const float4*)(G + (size_t)j1 * 32);
#pragma unroll
        for (int q = 0; q < 8; ++q) {
            const float4 a = r0[q], b = r1[q];
            h1[0][q * 4 + 0] = a.x; h1[0][q * 4 + 1] = a.y; h1[0][q * 4 + 2] = a.z; h1[0][q * 4 + 3] = a.w;
            h1[1][q * 4 + 0] = b.x; h1[1][q * 4 + 1] = b.y; h1[1][q * 4 + 2] = b.z; h1[1][q * 4 + 3] = b.w;
        }
    }
    const float4 x0 = ((const float4*)ppf)[(size_t)node * 16 + sub * 2 + 0];
    const float4 x1 = ((const float4*)ppf)[(size_t)node * 16 + sub * 2 + 1];
    const float xc0[4] = {x0.x, x0.y, x0.z, x0.w};
    const float xc1[4] = {x1.x, x1.y, x1.z, x1.w};
#pragma unroll
    for (int c = 0; c < 4; ++c) {
        const float a = xc0[c], b = xc1[c];
#pragma unroll
        for (int o = 0; o < 32; ++o) {
            const float w = W2a[(32 + c) * 32 + o];
            h1[0][o] += a * w;
            h1[1][o] += b * w;
        }
    }
#pragma unroll
    for (int o = 0; o < 32; ++o) {
        h1[0][o] = fmaxf(h1[0][o], 0.f);
        h1[1][o] = fmaxf(h1[1][o], 0.f);
    }

#pragma unroll 1
    for (int ob = 0; ob < 4; ++ob) {
        float a0[8], a1[8];
#pragma unroll
        for (int u = 0; u < 8; ++u) { const float b = b2b[ob * 8 + u]; a0[u] = b; a1[u] = b; }
#pragma unroll
        for (int hh = 0; hh < 32; ++hh) {
            const float h0v = h1[0][hh], h1v = h1[1][hh];
#pragma unroll
            for (int u = 0; u < 8; ++u) {
                const float w = W2b[hh * 32 + ob * 8 + u];
                a0[u] += h0v * w;
                a1[u] += h1v * w;
            }
        }
#pragma unroll
        for (int u = 0; u < 8; ++u) {
            float v = fmaxf(a0[u], a1[u]);
            v = fmaxf(v, __shfl_xor(v, 1));
            v = fmaxf(v, __shfl_xor(v, 2));
            v = fmaxf(v, __shfl_xor(v, 4));
            if (sub == 0) h2[(size_t)node * 32 + ob * 8 + u] = fmaxf(v, 0.f);
        }
    }
}

// ---------------------------------------------------------------------------
// K5: per-cloud global max pool (2048 x 32) + Linear(32,40).
// ---------------------------------------------------------------------------
__global__ __launch_bounds__(256) void pool_fc(const float* __restrict__ h2,
                                               const float* __restrict__ Wc,
                                               const float* __restrict__ bc,
                                               float* __restrict__ out) {
    const int b = blockIdx.x;
    const int tid = threadIdx.x;
    float pm[32];
#pragma unroll
    for (int o = 0; o < 32; ++o) pm[o] = -INFINITY;
    for (int s = 0; s < 8; ++s) {
        const int node = b * 2048 + s * 256 + tid;
        const float4* row = (const float4*)(h2 + (size_t)node * 32);
#pragma unroll
        for (int q = 0; q < 8; ++q) {
            const float4 v = row[q];
            pm[q * 4 + 0] = fmaxf(pm[q * 4 + 0], v.x);
            pm[q * 4 + 1] = fmaxf(pm[q * 4 + 1], v.y);
            pm[q * 4 + 2] = fmaxf(pm[q * 4 + 2], v.z);
            pm[q * 4 + 3] = fmaxf(pm[q * 4 + 3], v.w);
        }
    }
    __shared__ float red[256 * 33];
    __shared__ float pooled[32];
#pragma unroll
    for (int o = 0; o < 32; ++o) red[tid * 33 + o] = pm[o];
    __syncthreads();
    if (tid < 32) {
        float m = red[tid];
        for (int t = 1; t < 256; ++t) m = fmaxf(m, red[t * 33 + tid]);
        pooled[tid] = m;
    }
    __syncthreads();
    if (tid < 40) {
        float acc = bc[tid];
#pragma unroll
        for (int o = 0; o < 32; ++o) acc += pooled[o] * Wc[o * 40 + tid];
        out[b * 40 + tid] = acc;
    }
}

// ---------------------------------------------------------------------------
extern "C" void kernel_launch(void* const* d_in, const int* in_sizes, int n_in,
                              void* d_out, int out_size, void* d_ws, size_t ws_size,
                              hipStream_t stream) {
    const float* pos = (const float*)d_in[0];
    const float* nrm = (const float*)d_in[1];
    // d_in[2] = batch (implied by layout; unused)
    const float* W1a = (const float*)d_in[3];
    const float* b1a = (const float*)d_in[4];
    const float* W1b = (const float*)d_in[5];
    const float* b1b = (const float*)d_in[6];
    const float* W2a = (const float*)d_in[7];
    const float* b2a = (const float*)d_in[8];
    const float* W2b = (const float*)d_in[9];
    const float* b2b = (const float*)d_in[10];
    const float* Wc  = (const float*)d_in[11];
    const float* bc  = (const float*)d_in[12];
    float* out = (float*)d_out;

    char* ws = (char*)d_ws;
    float* pd  = (float*)(ws + OFF_PD);
    int*   piw = (int*)(ws + OFF_PI);
    int*   nbr = (int*)(ws + OFF_NBR);
    float* ppf = (float*)(ws + OFF_PPF);
    float* h   = (float*)(ws + OFF_H);   // reuses pd space (dead after merge)
    float* G   = (float*)(ws + OFF_G);   // reuses pi space (dead after merge)
    float* h2  = (float*)(ws + OFF_H2);

    hipLaunchKernelGGL(knn_partial,  dim3(256),  dim3(256), 0, stream, pos, pd, piw);
    hipLaunchKernelGGL(knn_merge_ppf, dim3(128), dim3(256), 0, stream, pos, nrm, pd, piw, nbr, ppf);
    hipLaunchKernelGGL(conv1_kernel, dim3(1024), dim3(256), 0, stream, ppf, W1a, b1a, W1b, b1b, h);
    hipLaunchKernelGGL(gfromh,       dim3(128),  dim3(256), 0, stream, h, W2a, b2a, G);
    hipLaunchKernelGGL(conv2_kernel, dim3(1024), dim3(256), 0, stream, ppf, nbr, G, W2a, W2b, b2b, h2);
    hipLaunchKernelGGL(pool_fc,      dim3(16),   dim3(256), 0, stream, h2, Wc, bc, out);
}

// Round 2
// 346.019 us; speedup vs baseline: 2.4053x; 2.4053x over previous
//
#include <hip/hip_runtime.h>
#include <math.h>

// ---------------------------------------------------------------------------
// PPFNet pipeline on MI355X. B=16 clouds x 2048 pts, K=16 knn, all f32.
//  K1 knn_ppf : one kernel does exact knn + neighbor indices + PPF features.
//     Phase A: 8 slices/point, branchless med3 top-16 of DISTANCES only
//              (1 v_med3_f32 per slot per candidate, no divergence).
//     Phase B: merge 8 slice lists -> exact 16th-smallest threshold tau.
//     Phase C: rescan with bit-identical d2, collect hits (d2<=tau) to LDS.
//     Phase D: rare tie-handling selection via packed (d2,idx) u64 keys.
//     Phase E: write nbr + ppf.
//     Neighbor ORDER doesn't matter downstream (max aggregation) - only the
//     SET, with ties at tau broken by lower index (matches stable top_k).
//  K3 conv1   : 8 threads/node (2 edges each), MLP(4->32->32), max, relu
//  K4a gfromh : G = h @ W2a[0:32] + b2a   (hoists conv2 layer1 out of edges)
//  K4b conv2  : per-edge: relu(G[j] + ppf@W2a[32:36]) -> 32x32 -> max, relu
//  K5 pool_fc : per-cloud max pool + Linear(32,40)
// ---------------------------------------------------------------------------

#define NPER 2048
#define NCLOUD 16
#define NPTS (NPER * NCLOUD)

// ws layout (bytes)
#define OFF_NBR  (size_t)(0u)          // int   [N][16]   (2 MB)
#define OFF_PPF  (size_t)(2u << 20)    // float [N][16][4](8 MB)
#define OFF_H    (size_t)(10u << 20)   // float [N][32]   (4 MB)
#define OFF_G    (size_t)(14u << 20)   // float [N][32]   (4 MB)
#define OFF_H2   (size_t)(18u << 20)   // float [N][32]   (4 MB) -> 22 MB

__device__ __forceinline__ float med3(float a, float b, float c) {
    return __builtin_amdgcn_fmed3f(a, b, c);
}

__device__ __forceinline__ float angf(float ax, float ay, float az,
                                      float bx, float by, float bz) {
    const float cx = ay * bz - az * by;
    const float cy = az * bx - ax * bz;
    const float cz = ax * by - ay * bx;
    const float cn = sqrtf(cx * cx + cy * cy + cz * cz);
    const float dt = ax * bx + ay * by + az * bz;
    return atan2f(cn, dt);
}

// ---------------------------------------------------------------------------
// K1: knn + ppf. Block = 256 threads = 32 points x 8 slices. Grid = 1024.
// ---------------------------------------------------------------------------
__global__ __launch_bounds__(256) void knn_ppf(const float* __restrict__ pos,
                                               const float* __restrict__ nrm,
                                               int* __restrict__ nbr,
                                               float* __restrict__ ppf) {
    const int tid = threadIdx.x;
    const int pl  = tid >> 3;               // point within block (0..31)
    const int sl  = tid & 7;                // slice (0..7)
    const int gp  = blockIdx.x * 32 + pl;   // global point
    const int cloud = gp >> 11;
    const int lp  = gp & 2047;              // local point idx in cloud
    const int cb3 = cloud * NPER * 3;

    __shared__ float tile[768];             // 256 candidates x xyz
    __shared__ float fl[256][16];           // per-slice sorted top-16 dists
    __shared__ float b2v[64][16];           // half-merged lists (2 per point)
    __shared__ float hd[32][24];            // hit distances
    __shared__ int   hiL[32][24];           // hit local indices
    __shared__ int   cnt[32];
    __shared__ float tauv[32];

    const float px = pos[gp * 3 + 0];
    const float py = pos[gp * 3 + 1];
    const float pz = pos[gp * 3 + 2];

    if (tid < 32) cnt[tid] = 0;

    float dl[16];
#pragma unroll
    for (int m = 0; m < 16; ++m) dl[m] = INFINITY;

    // ---- Phase A: branchless med3 top-16 distances, 256 cands per slice ----
#pragma unroll 1
    for (int t = 0; t < 8; ++t) {
        __syncthreads();
        tile[tid]       = pos[cb3 + t * 768 + tid];
        tile[tid + 256] = pos[cb3 + t * 768 + tid + 256];
        tile[tid + 512] = pos[cb3 + t * 768 + tid + 512];
        __syncthreads();
#pragma unroll 4
        for (int jj = 0; jj < 32; ++jj) {
            const int cl = jj * 8 + sl;
            const float cx = tile[3 * cl + 0];
            const float cy = tile[3 * cl + 1];
            const float cz = tile[3 * cl + 2];
            const float dx = __fsub_rn(px, cx);
            const float dy = __fsub_rn(py, cy);
            const float dz = __fsub_rn(pz, cz);
            float d2 = __fadd_rn(__fadd_rn(__fmul_rn(dx, dx), __fmul_rn(dy, dy)),
                                 __fmul_rn(dz, dz));
            const int cand = t * 256 + cl;
            d2 = (cand == lp) ? INFINITY : d2;   // no self loop
#pragma unroll
            for (int m = 15; m >= 1; --m) dl[m] = med3(dl[m - 1], dl[m], d2);
            dl[0] = fminf(dl[0], d2);
        }
    }
#pragma unroll
    for (int m = 0; m < 16; ++m) fl[tid][m] = dl[m];
    __syncthreads();

    // ---- Phase B1: 2 threads/point each merge 4 slice lists (64 vals) ----
    if (tid < 64) {
        const int p = tid >> 1, hf = tid & 1;
        float d2l[16];
#pragma unroll
        for (int m = 0; m < 16; ++m) d2l[m] = INFINITY;
        const int r0 = p * 8 + hf * 4;
#pragma unroll 1
        for (int r = r0; r < r0 + 4; ++r) {
#pragma unroll
            for (int s = 0; s < 16; ++s) {
                const float v = fl[r][s];
#pragma unroll
                for (int m = 15; m >= 1; --m) d2l[m] = med3(d2l[m - 1], d2l[m], v);
                d2l[0] = fminf(d2l[0], v);
            }
        }
#pragma unroll
        for (int m = 0; m < 16; ++m) b2v[tid][m] = d2l[m];
    }
    __syncthreads();

    // ---- Phase B2: exact 16th smallest of two sorted 16-lists ----
    if (tid < 32) {
        const float* a = b2v[2 * tid];
        const float* b = b2v[2 * tid + 1];
        float tv = fminf(a[15], b[15]);
#pragma unroll
        for (int k = 1; k <= 15; ++k) tv = fminf(tv, fmaxf(a[k - 1], b[15 - k]));
        tauv[tid] = tv;
    }
    __syncthreads();

    const float taup = tauv[pl];

    // ---- Phase C: rescan (bit-identical d2), collect hits <= tau ----
#pragma unroll 1
    for (int t = 0; t < 8; ++t) {
        __syncthreads();
        tile[tid]       = pos[cb3 + t * 768 + tid];
        tile[tid + 256] = pos[cb3 + t * 768 + tid + 256];
        tile[tid + 512] = pos[cb3 + t * 768 + tid + 512];
        __syncthreads();
#pragma unroll 4
        for (int jj = 0; jj < 32; ++jj) {
            const int cl = jj * 8 + sl;
            const float cx = tile[3 * cl + 0];
            const float cy = tile[3 * cl + 1];
            const float cz = tile[3 * cl + 2];
            const float dx = __fsub_rn(px, cx);
            const float dy = __fsub_rn(py, cy);
            const float dz = __fsub_rn(pz, cz);
            float d2 = __fadd_rn(__fadd_rn(__fmul_rn(dx, dx), __fmul_rn(dy, dy)),
                                 __fmul_rn(dz, dz));
            const int cand = t * 256 + cl;
            d2 = (cand == lp) ? INFINITY : d2;
            if (d2 <= taup) {
                const int s = atomicAdd(&cnt[pl], 1);
                if (s < 24) { hd[pl][s] = d2; hiL[pl][s] = cand; }
            }
        }
    }
    __syncthreads();

    // ---- Phase D: if ties pushed count past 16, select exact 16 ----
    if (tid < 32) {
        const int n = cnt[tid];
        if (n != 16) {
            const int sel = n < 24 ? n : 24;
            unsigned long long keys[16];
#pragma unroll
            for (int m = 0; m < 16; ++m) keys[m] = ~0ULL;
            for (int s = 0; s < sel; ++s) {
                const unsigned int db = __float_as_uint(hd[tid][s]);
                const unsigned long long key =
                    ((unsigned long long)db << 32) | (unsigned int)hiL[tid][s];
                if (key < keys[15]) {
#pragma unroll
                    for (int m = 15; m >= 1; --m) {
                        const bool up   = key < keys[m - 1];
                        const bool here = key < keys[m];
                        keys[m] = up ? keys[m - 1] : (here ? key : keys[m]);
                    }
                    if (key < keys[0]) keys[0] = key;
                }
            }
#pragma unroll
            for (int m = 0; m < 16; ++m)
                hiL[tid][m] = (int)(unsigned int)(keys[m] & 0xFFFFFFFFu);
        }
    }
    __syncthreads();

    // ---- Phase E: nbr + ppf (2 edges per thread) ----
    const int cbase = cloud * NPER;
    const float nix = nrm[gp * 3 + 0], niy = nrm[gp * 3 + 1], niz = nrm[gp * 3 + 2];
#pragma unroll
    for (int e = 0; e < 2; ++e) {
        const int m = sl * 2 + e;
        const int j = cbase + hiL[pl][m];
        nbr[gp * 16 + m] = j;
        const float pjx = pos[j * 3 + 0], pjy = pos[j * 3 + 1], pjz = pos[j * 3 + 2];
        const float njx = nrm[j * 3 + 0], njy = nrm[j * 3 + 1], njz = nrm[j * 3 + 2];
        const float dx = pjx - px, dy = pjy - py, dz = pjz - pz;
        float4 v;
        v.x = sqrtf(dx * dx + dy * dy + dz * dz);
        v.y = angf(nix, niy, niz, dx, dy, dz);
        v.z = angf(njx, njy, njz, dx, dy, dz);
        v.w = angf(nix, niy, niz, njx, njy, njz);
        ((float4*)ppf)[(size_t)gp * 16 + m] = v;
    }
}

// ---------------------------------------------------------------------------
// K3: conv1. 8 threads/node, 2 edges each. MLP(4->32)->relu->(32->32),
// max over edges (thread-local then shfl_xor across 8-lane group), relu.
// ---------------------------------------------------------------------------
__global__ __launch_bounds__(256) void conv1_kernel(const float* __restrict__ ppf,
                                                    const float* __restrict__ W1a,
                                                    const float* __restrict__ b1a,
                                                    const float* __restrict__ W1b,
                                                    const float* __restrict__ b1b,
                                                    float* __restrict__ h) {
    const int gid  = blockIdx.x * 256 + threadIdx.x;
    const int node = gid >> 3;
    const int sub  = gid & 7;

    const float4 x0 = ((const float4*)ppf)[(size_t)node * 16 + sub * 2 + 0];
    const float4 x1 = ((const float4*)ppf)[(size_t)node * 16 + sub * 2 + 1];

    float h1[2][32];
#pragma unroll
    for (int o = 0; o < 32; ++o) {
        const float w0 = W1a[o], w1 = W1a[32 + o], w2 = W1a[64 + o], w3 = W1a[96 + o];
        const float b = b1a[o];
        h1[0][o] = fmaxf(b + x0.x * w0 + x0.y * w1 + x0.z * w2 + x0.w * w3, 0.f);
        h1[1][o] = fmaxf(b + x1.x * w0 + x1.y * w1 + x1.z * w2 + x1.w * w3, 0.f);
    }

#pragma unroll 1
    for (int ob = 0; ob < 4; ++ob) {
        float a0[8], a1[8];
#pragma unroll
        for (int u = 0; u < 8; ++u) { const float b = b1b[ob * 8 + u]; a0[u] = b; a1[u] = b; }
#pragma unroll
        for (int hh = 0; hh < 32; ++hh) {
            const float h0v = h1[0][hh], h1v = h1[1][hh];
#pragma unroll
            for (int u = 0; u < 8; ++u) {
                const float w = W1b[hh * 32 + ob * 8 + u];
                a0[u] += h0v * w;
                a1[u] += h1v * w;
            }
        }
#pragma unroll
        for (int u = 0; u < 8; ++u) {
            float v = fmaxf(a0[u], a1[u]);
            v = fmaxf(v, __shfl_xor(v, 1));
            v = fmaxf(v, __shfl_xor(v, 2));
            v = fmaxf(v, __shfl_xor(v, 4));
            if (sub == 0) h[(size_t)node * 32 + ob * 8 + u] = fmaxf(v, 0.f);
        }
    }
}

// ---------------------------------------------------------------------------
// K4a: G = h @ W2a[0:32,:] + b2a  (per node)
// ---------------------------------------------------------------------------
__global__ __launch_bounds__(256) void gfromh(const float* __restrict__ h,
                                              const float* __restrict__ W2a,
                                              const float* __restrict__ b2a,
                                              float* __restrict__ G) {
    const int n = blockIdx.x * 256 + threadIdx.x;
    float hr[32];
    const float4* row = (const float4*)(h + (size_t)n * 32);
#pragma unroll
    for (int q = 0; q < 8; ++q) {
        const float4 v = row[q];
        hr[q * 4 + 0] = v.x; hr[q * 4 + 1] = v.y; hr[q * 4 + 2] = v.z; hr[q * 4 + 3] = v.w;
    }
    float acc[32];
#pragma unroll
    for (int o = 0; o < 32; ++o) acc[o] = b2a[o];
#pragma unroll
    for (int c = 0; c < 32; ++c) {
        const float hv = hr[c];
#pragma unroll
        for (int o = 0; o < 32; ++o) acc[o] += hv * W2a[c * 32 + o];
    }
    float4* go = (float4*)(G + (size_t)n * 32);
#pragma unroll
    for (int q = 0; q < 8; ++q) {
        float4 v;
        v.x = acc[q * 4 + 0]; v.y = acc[q * 4 + 1]; v.z = acc[q * 4 + 2]; v.w = acc[q * 4 + 3];
        go[q] = v;
    }
}

// ---------------------------------------------------------------------------
// K4b: conv2 per-edge: relu(G[j] + ppf @ W2a[32:36,:]) -> 32x32 -> max, relu.
// ---------------------------------------------------------------------------
__global__ __launch_bounds__(256) void conv2_kernel(const float* __restrict__ ppf,
                                                    const int* __restrict__ nbr,
                                                    const float* __restrict__ G,
                                                    const float* __restrict__ W2a,
                                                    const float* __restrict__ W2b,
                                                    const float* __restrict__ b2b,
                                                    float* __restrict__ h2) {
    const int gid  = blockIdx.x * 256 + threadIdx.x;
    const int node = gid >> 3;
    const int sub  = gid & 7;

    const int j0 = nbr[node * 16 + sub * 2 + 0];
    const int j1 = nbr[node * 16 + sub * 2 + 1];

    float h1[2][32];
    {
        const float4* r0 = (const float4*)(G + (size_t)j0 * 32);
        const float4* r1 = (const float4*)(G + (size_t)j1 * 32);
#pragma unroll
        for (int q = 0; q < 8; ++q) {
            const float4 a = r0[q], b = r1[q];
            h1[0][q * 4 + 0] = a.x; h1[0][q * 4 + 1] = a.y; h1[0][q * 4 + 2] = a.z; h1[0][q * 4 + 3] = a.w;
            h1[1][q * 4 + 0] = b.x; h1[1][q * 4 + 1] = b.y; h1[1][q * 4 + 2] = b.z; h1[1][q * 4 + 3] = b.w;
        }
    }
    const float4 x0 = ((const float4*)ppf)[(size_t)node * 16 + sub * 2 + 0];
    const float4 x1 = ((const float4*)ppf)[(size_t)node * 16 + sub * 2 + 1];
    const float xc0[4] = {x0.x, x0.y, x0.z, x0.w};
    const float xc1[4] = {x1.x, x1.y, x1.z, x1.w};
#pragma unroll
    for (int c = 0; c < 4; ++c) {
        const float a = xc0[c], b = xc1[c];
#pragma unroll
        for (int o = 0; o < 32; ++o) {
            const float w = W2a[(32 + c) * 32 + o];
            h1[0][o] += a * w;
            h1[1][o] += b * w;
        }
    }
#pragma unroll
    for (int o = 0; o < 32; ++o) {
        h1[0][o] = fmaxf(h1[0][o], 0.f);
        h1[1][o] = fmaxf(h1[1][o], 0.f);
    }

#pragma unroll 1
    for (int ob = 0; ob < 4; ++ob) {
        float a0[8], a1[8];
#pragma unroll
        for (int u = 0; u < 8; ++u) { const float b = b2b[ob * 8 + u]; a0[u] = b; a1[u] = b; }
#pragma unroll
        for (int hh = 0; hh < 32; ++hh) {
            const float h0v = h1[0][hh], h1v = h1[1][hh];
#pragma unroll
            for (int u = 0; u < 8; ++u) {
                const float w = W2b[hh * 32 + ob * 8 + u];
                a0[u] += h0v * w;
                a1[u] += h1v * w;
            }
        }
#pragma unroll
        for (int u = 0; u < 8; ++u) {
            float v = fmaxf(a0[u], a1[u]);
            v = fmaxf(v, __shfl_xor(v, 1));
            v = fmaxf(v, __shfl_xor(v, 2));
            v = fmaxf(v, __shfl_xor(v, 4));
            if (sub == 0) h2[(size_t)node * 32 + ob * 8 + u] = fmaxf(v, 0.f);
        }
    }
}

// ---------------------------------------------------------------------------
// K5: per-cloud global max pool (2048 x 32) + Linear(32,40).
// ---------------------------------------------------------------------------
__global__ __launch_bounds__(256) void pool_fc(const float* __restrict__ h2,
                                               const float* __restrict__ Wc,
                                               const float* __restrict__ bc,
                                               float* __restrict__ out) {
    const int b = blockIdx.x;
    const int tid = threadIdx.x;
    float pm[32];
#pragma unroll
    for (int o = 0; o < 32; ++o) pm[o] = -INFINITY;
    for (int s = 0; s < 8; ++s) {
        const int node = b * 2048 + s * 256 + tid;
        const float4* row = (const float4*)(h2 + (size_t)node * 32);
#pragma unroll
        for (int q = 0; q < 8; ++q) {
            const float4 v = row[q];
            pm[q * 4 + 0] = fmaxf(pm[q * 4 + 0], v.x);
            pm[q * 4 + 1] = fmaxf(pm[q * 4 + 1], v.y);
            pm[q * 4 + 2] = fmaxf(pm[q * 4 + 2], v.z);
            pm[q * 4 + 3] = fmaxf(pm[q * 4 + 3], v.w);
        }
    }
    __shared__ float red[256 * 33];
    __shared__ float pooled[32];
#pragma unroll
    for (int o = 0; o < 32; ++o) red[tid * 33 + o] = pm[o];
    __syncthreads();
    if (tid < 32) {
        float m = red[tid];
        for (int t = 1; t < 256; ++t) m = fmaxf(m, red[t * 33 + tid]);
        pooled[tid] = m;
    }
    __syncthreads();
    if (tid < 40) {
        float acc = bc[tid];
#pragma unroll
        for (int o = 0; o < 32; ++o) acc += pooled[o] * Wc[o * 40 + tid];
        out[b * 40 + tid] = acc;
    }
}

// ---------------------------------------------------------------------------
extern "C" void kernel_launch(void* const* d_in, const int* in_sizes, int n_in,
                              void* d_out, int out_size, void* d_ws, size_t ws_size,
                              hipStream_t stream) {
    const float* pos = (const float*)d_in[0];
    const float* nrm = (const float*)d_in[1];
    const float* W1a = (const float*)d_in[3];
    const float* b1a = (const float*)d_in[4];
    const float* W1b = (const float*)d_in[5];
    const float* b1b = (const float*)d_in[6];
    const float* W2a = (const float*)d_in[7];
    const float* b2a = (const float*)d_in[8];
    const float* W2b = (const float*)d_in[9];
    const float* b2b = (const float*)d_in[10];
    const float* Wc  = (const float*)d_in[11];
    const float* bc  = (const float*)d_in[12];
    float* out = (float*)d_out;

    char* ws = (char*)d_ws;
    int*   nbr = (int*)(ws + OFF_NBR);
    float* ppf = (float*)(ws + OFF_PPF);
    float* h   = (float*)(ws + OFF_H);
    float* G   = (float*)(ws + OFF_G);
    float* h2  = (float*)(ws + OFF_H2);

    hipLaunchKernelGGL(knn_ppf,      dim3(1024), dim3(256), 0, stream, pos, nrm, nbr, ppf);
    hipLaunchKernelGGL(conv1_kernel, dim3(1024), dim3(256), 0, stream, ppf, W1a, b1a, W1b, b1b, h);
    hipLaunchKernelGGL(gfromh,       dim3(128),  dim3(256), 0, stream, h, W2a, b2a, G);
    hipLaunchKernelGGL(conv2_kernel, dim3(1024), dim3(256), 0, stream, ppf, nbr, G, W2a, W2b, b2b, h2);
    hipLaunchKernelGGL(pool_fc,      dim3(16),   dim3(256), 0, stream, h2, Wc, bc, out);
}

// Round 3
// 301.162 us; speedup vs baseline: 2.7636x; 1.1489x over previous
//
#include <hip/hip_runtime.h>
#include <math.h>

// ---------------------------------------------------------------------------
// PPFNet pipeline on MI355X. B=16 clouds x 2048 pts, K=16 knn, all f32.
//  K1 knn_ppf : whole cloud resident in LDS as float4{x,y,z,|c|^2}.
//     Phase A: 8 slices/point, branchless med3 top-8 of s = |c|^2 - 2 p.c
//              (3 FMA + 8 med3 per candidate, one ds_read_b128).
//     Phase B: in-wave bitonic shuffle merge of the 8 slice lists -> tau_s
//              (16th smallest kept s; >= true 16th, off by <= 8 ranks).
//     Phase C: rescan on s with widened tau, collect hit indices to LDS.
//     Phase D: points with cnt != 16: exact d2 (bit-identical to numpy form)
//              + index-tiebreak select of the true top-16.
//     Phase E: write nbr + ppf.
//  K3 conv1   : 8 threads/node (2 edges each), MLP(4->32->32), max, relu
//  K4a gfromh : G = h @ W2a[0:32] + b2a (hoists conv2 layer1 out of edges)
//  K4b conv2  : per-edge: relu(G[j] + ppf@W2a[32:36]) -> 32x32 -> max, relu
//  K5 pool_fc : per-cloud max pool (tree reduce) + Linear(32,40)
// ---------------------------------------------------------------------------

#define NPER 2048
#define NCLOUD 16

// ws layout (bytes)
#define OFF_NBR  (size_t)(0u)          // int   [N][16]   (2 MB)
#define OFF_PPF  (size_t)(2u << 20)    // float [N][16][4](8 MB)
#define OFF_H    (size_t)(10u << 20)   // float [N][32]   (4 MB)
#define OFF_G    (size_t)(14u << 20)   // float [N][32]   (4 MB)
#define OFF_H2   (size_t)(18u << 20)   // float [N][32]   (4 MB) -> 22 MB

__device__ __forceinline__ float med3(float a, float b, float c) {
    return __builtin_amdgcn_fmed3f(a, b, c);
}
__device__ __forceinline__ void cex(float& a, float& b) {
    const float lo = fminf(a, b), hi = fmaxf(a, b); a = lo; b = hi;
}
// Sort a bitonic 16-sequence ascending (4-stage bitonic merge network).
__device__ __forceinline__ void bmerge16(float (&v)[16]) {
#pragma unroll
    for (int i = 0; i < 8; ++i) cex(v[i], v[i + 8]);
#pragma unroll
    for (int b = 0; b < 16; b += 8)
#pragma unroll
        for (int i = 0; i < 4; ++i) cex(v[b + i], v[b + i + 4]);
#pragma unroll
    for (int b = 0; b < 16; b += 4)
#pragma unroll
        for (int i = 0; i < 2; ++i) cex(v[b + i], v[b + i + 2]);
#pragma unroll
    for (int b = 0; b < 16; b += 2) cex(v[b], v[b + 1]);
}

__device__ __forceinline__ float angf(float ax, float ay, float az,
                                      float bx, float by, float bz) {
    const float cx = ay * bz - az * by;
    const float cy = az * bx - ax * bz;
    const float cz = ax * by - ay * bx;
    const float cn = sqrtf(cx * cx + cy * cy + cz * cz);
    const float dt = ax * bx + ay * by + az * bz;
    return atan2f(cn, dt);
}

// ---------------------------------------------------------------------------
// K1: knn + ppf. Block = 256 threads = 32 points x 8 slices. Grid = 1024.
// LDS: 32KB tile + 5KB hits = ~38KB -> 4 blocks/CU (LDS-wise).
// ---------------------------------------------------------------------------
__global__ __launch_bounds__(256) void knn_ppf(const float* __restrict__ pos,
                                               const float* __restrict__ nrm,
                                               int* __restrict__ nbr,
                                               float* __restrict__ ppf) {
    const int tid = threadIdx.x;
    const int pl  = tid >> 3;               // point within block (0..31)
    const int sl  = tid & 7;                // slice (0..7)
    const int gp  = blockIdx.x * 32 + pl;   // global point
    const int cloud = gp >> 11;
    const int lp  = gp & 2047;              // local point idx in cloud
    const int cbase = cloud * NPER;

    __shared__ float4 tile[2048];           // x,y,z,|c|^2  (32 KB)
    __shared__ int    hiL[32][40];          // hit local indices (5 KB)
    __shared__ int    cnt[32];

    if (tid < 32) cnt[tid] = 0;

    // ---- stage whole cloud into LDS (once) ----
#pragma unroll
    for (int c = 0; c < 8; ++c) {
        const int idx = c * 256 + tid;
        const float x = pos[(cbase + idx) * 3 + 0];
        const float y = pos[(cbase + idx) * 3 + 1];
        const float z = pos[(cbase + idx) * 3 + 2];
        tile[idx] = make_float4(x, y, z, x * x + y * y + z * z);
    }
    __syncthreads();

    const float4 P  = tile[lp];
    const float pn2 = P.w;
    const float m2x = -2.f * P.x, m2y = -2.f * P.y, m2z = -2.f * P.z;

    // ---- Phase A: top-8 of s per slice, branchless med3 ----
    float dl[8];
#pragma unroll
    for (int m = 0; m < 8; ++m) dl[m] = INFINITY;

#pragma unroll 4
    for (int jj = 0; jj < 256; ++jj) {
        const int cand = jj * 8 + sl;
        const float4 C = tile[cand];
        float s = fmaf(m2x, C.x, fmaf(m2y, C.y, fmaf(m2z, C.z, C.w)));
        s = (cand == lp) ? INFINITY : s;
#pragma unroll
        for (int m = 7; m >= 1; --m) dl[m] = med3(dl[m - 1], dl[m], s);
        dl[0] = fminf(dl[0], s);
    }

    // ---- Phase B: in-wave bitonic merge of the point's 8 slice lists ----
    // round 1 (xor 1): two sorted-8 -> sorted-16
    float v[16];
#pragma unroll
    for (int i = 0; i < 8; ++i) v[i] = dl[i];
#pragma unroll
    for (int i = 0; i < 8; ++i) v[15 - i] = __shfl_xor(dl[i], 1);
    bmerge16(v);
    // round 2 (xor 2): keep lowest-16 of 32, re-sort
    {
        float p[16];
#pragma unroll
        for (int i = 0; i < 16; ++i) p[i] = __shfl_xor(v[i], 2);
        float w[16];
#pragma unroll
        for (int i = 0; i < 16; ++i) w[i] = fminf(v[i], p[15 - i]);
        bmerge16(w);
#pragma unroll
        for (int i = 0; i < 16; ++i) v[i] = w[i];
    }
    // round 3 (xor 4): tau_s = max of lowest-16 set
    float tau_s;
    {
        float p[16];
#pragma unroll
        for (int i = 0; i < 16; ++i) p[i] = __shfl_xor(v[i], 4);
        float t = -INFINITY;
#pragma unroll
        for (int i = 0; i < 16; ++i) t = fmaxf(t, fminf(v[i], p[15 - i]));
        tau_s = t;
    }
    // widen: covers s-form vs exact-d2 rounding discrepancy (100x margin)
    const float tsw = tau_s + 6e-5f * (1.f + pn2 + fabsf(tau_s + pn2));

    // ---- Phase C: rescan on s, collect hit indices ----
#pragma unroll 4
    for (int jj = 0; jj < 256; ++jj) {
        const int cand = jj * 8 + sl;
        const float4 C = tile[cand];
        const float s = fmaf(m2x, C.x, fmaf(m2y, C.y, fmaf(m2z, C.z, C.w)));
        if (s <= tsw && cand != lp) {
            const int k = atomicAdd(&cnt[pl], 1);
            if (k < 40) hiL[pl][k] = cand;
        }
    }
    __syncthreads();

    // ---- Phase D: exact top-16 (bit-identical d2, index tiebreak) ----
    if (tid < 32) {
        int n = cnt[tid];
        n = n > 40 ? 40 : n;
        if (n != 16) {
            const int myl = (blockIdx.x * 32 + tid) & 2047;
            const float4 Q = tile[myl];
            unsigned long long keys[16];
#pragma unroll
            for (int m = 0; m < 16; ++m) keys[m] = ~0ULL;
            for (int i = 0; i < n; ++i) {
                const int cand = hiL[tid][i];
                const float4 C = tile[cand];
                const float dx = __fsub_rn(Q.x, C.x);
                const float dy = __fsub_rn(Q.y, C.y);
                const float dz = __fsub_rn(Q.z, C.z);
                const float d2 = __fadd_rn(__fadd_rn(__fmul_rn(dx, dx),
                                                     __fmul_rn(dy, dy)),
                                           __fmul_rn(dz, dz));
                const unsigned long long key =
                    ((unsigned long long)__float_as_uint(d2) << 32) |
                    (unsigned int)cand;
                if (key < keys[15]) {
#pragma unroll
                    for (int m = 15; m >= 1; --m) {
                        const bool up   = key < keys[m - 1];
                        const bool here = key < keys[m];
                        keys[m] = up ? keys[m - 1] : (here ? key : keys[m]);
                    }
                    if (key < keys[0]) keys[0] = key;
                }
            }
#pragma unroll
            for (int m = 0; m < 16; ++m)
                hiL[tid][m] = (int)(unsigned int)(keys[m] & 0xFFFFFFFFu);
        }
    }
    __syncthreads();

    // ---- Phase E: nbr + ppf (2 edges per thread) ----
    const float nix = nrm[gp * 3 + 0], niy = nrm[gp * 3 + 1], niz = nrm[gp * 3 + 2];
    const float px = P.x, py = P.y, pz = P.z;
#pragma unroll
    for (int e = 0; e < 2; ++e) {
        const int m = sl * 2 + e;
        const int j = cbase + hiL[pl][m];
        nbr[gp * 16 + m] = j;
        const float pjx = pos[j * 3 + 0], pjy = pos[j * 3 + 1], pjz = pos[j * 3 + 2];
        const float njx = nrm[j * 3 + 0], njy = nrm[j * 3 + 1], njz = nrm[j * 3 + 2];
        const float dx = pjx - px, dy = pjy - py, dz = pjz - pz;
        float4 o;
        o.x = sqrtf(dx * dx + dy * dy + dz * dz);
        o.y = angf(nix, niy, niz, dx, dy, dz);
        o.z = angf(njx, njy, njz, dx, dy, dz);
        o.w = angf(nix, niy, niz, njx, njy, njz);
        ((float4*)ppf)[(size_t)gp * 16 + m] = o;
    }
}

// ---------------------------------------------------------------------------
// K3: conv1. 8 threads/node, 2 edges each. MLP(4->32)->relu->(32->32),
// max over edges (thread-local then shfl_xor across 8-lane group), relu.
// ---------------------------------------------------------------------------
__global__ __launch_bounds__(256) void conv1_kernel(const float* __restrict__ ppf,
                                                    const float* __restrict__ W1a,
                                                    const float* __restrict__ b1a,
                                                    const float* __restrict__ W1b,
                                                    const float* __restrict__ b1b,
                                                    float* __restrict__ h) {
    const int gid  = blockIdx.x * 256 + threadIdx.x;
    const int node = gid >> 3;
    const int sub  = gid & 7;

    const float4 x0 = ((const float4*)ppf)[(size_t)node * 16 + sub * 2 + 0];
    const float4 x1 = ((const float4*)ppf)[(size_t)node * 16 + sub * 2 + 1];

    float h1[2][32];
#pragma unroll
    for (int o = 0; o < 32; ++o) {
        const float w0 = W1a[o], w1 = W1a[32 + o], w2 = W1a[64 + o], w3 = W1a[96 + o];
        const float b = b1a[o];
        h1[0][o] = fmaxf(b + x0.x * w0 + x0.y * w1 + x0.z * w2 + x0.w * w3, 0.f);
        h1[1][o] = fmaxf(b + x1.x * w0 + x1.y * w1 + x1.z * w2 + x1.w * w3, 0.f);
    }

#pragma unroll 1
    for (int ob = 0; ob < 4; ++ob) {
        float a0[8], a1[8];
#pragma unroll
        for (int u = 0; u < 8; ++u) { const float b = b1b[ob * 8 + u]; a0[u] = b; a1[u] = b; }
#pragma unroll
        for (int hh = 0; hh < 32; ++hh) {
            const float h0v = h1[0][hh], h1v = h1[1][hh];
#pragma unroll
            for (int u = 0; u < 8; ++u) {
                const float w = W1b[hh * 32 + ob * 8 + u];
                a0[u] += h0v * w;
                a1[u] += h1v * w;
            }
        }
#pragma unroll
        for (int u = 0; u < 8; ++u) {
            float v = fmaxf(a0[u], a1[u]);
            v = fmaxf(v, __shfl_xor(v, 1));
            v = fmaxf(v, __shfl_xor(v, 2));
            v = fmaxf(v, __shfl_xor(v, 4));
            if (sub == 0) h[(size_t)node * 32 + ob * 8 + u] = fmaxf(v, 0.f);
        }
    }
}

// ---------------------------------------------------------------------------
// K4a: G = h @ W2a[0:32,:] + b2a  (per node)
// ---------------------------------------------------------------------------
__global__ __launch_bounds__(256) void gfromh(const float* __restrict__ h,
                                              const float* __restrict__ W2a,
                                              const float* __restrict__ b2a,
                                              float* __restrict__ G) {
    const int n = blockIdx.x * 256 + threadIdx.x;
    float hr[32];
    const float4* row = (const float4*)(h + (size_t)n * 32);
#pragma unroll
    for (int q = 0; q < 8; ++q) {
        const float4 v = row[q];
        hr[q * 4 + 0] = v.x; hr[q * 4 + 1] = v.y; hr[q * 4 + 2] = v.z; hr[q * 4 + 3] = v.w;
    }
    float acc[32];
#pragma unroll
    for (int o = 0; o < 32; ++o) acc[o] = b2a[o];
#pragma unroll
    for (int c = 0; c < 32; ++c) {
        const float hv = hr[c];
#pragma unroll
        for (int o = 0; o < 32; ++o) acc[o] += hv * W2a[c * 32 + o];
    }
    float4* go = (float4*)(G + (size_t)n * 32);
#pragma unroll
    for (int q = 0; q < 8; ++q) {
        float4 v;
        v.x = acc[q * 4 + 0]; v.y = acc[q * 4 + 1]; v.z = acc[q * 4 + 2]; v.w = acc[q * 4 + 3];
        go[q] = v;
    }
}

// ---------------------------------------------------------------------------
// K4b: conv2 per-edge: relu(G[j] + ppf @ W2a[32:36,:]) -> 32x32 -> max, relu.
// ---------------------------------------------------------------------------
__global__ __launch_bounds__(256) void conv2_kernel(const float* __restrict__ ppf,
                                                    const int* __restrict__ nbr,
                                                    const float* __restrict__ G,
                                                    const float* __restrict__ W2a,
                                                    const float* __restrict__ W2b,
                                                    const float* __restrict__ b2b,
                                                    float* __restrict__ h2) {
    const int gid  = blockIdx.x * 256 + threadIdx.x;
    const int node = gid >> 3;
    const int sub  = gid & 7;

    const int j0 = nbr[node * 16 + sub * 2 + 0];
    const int j1 = nbr[node * 16 + sub * 2 + 1];

    float h1[2][32];
    {
        const float4* r0 = (const float4*)(G + (size_t)j0 * 32);
        const float4* r1 = (const float4*)(G + (size_t)j1 * 32);
#pragma unroll
        for (int q = 0; q < 8; ++q) {
            const float4 a = r0[q], b = r1[q];
            h1[0][q * 4 + 0] = a.x; h1[0][q * 4 + 1] = a.y; h1[0][q * 4 + 2] = a.z; h1[0][q * 4 + 3] = a.w;
            h1[1][q * 4 + 0] = b.x; h1[1][q * 4 + 1] = b.y; h1[1][q * 4 + 2] = b.z; h1[1][q * 4 + 3] = b.w;
        }
    }
    const float4 x0 = ((const float4*)ppf)[(size_t)node * 16 + sub * 2 + 0];
    const float4 x1 = ((const float4*)ppf)[(size_t)node * 16 + sub * 2 + 1];
    const float xc0[4] = {x0.x, x0.y, x0.z, x0.w};
    const float xc1[4] = {x1.x, x1.y, x1.z, x1.w};
#pragma unroll
    for (int c = 0; c < 4; ++c) {
        const float a = xc0[c], b = xc1[c];
#pragma unroll
        for (int o = 0; o < 32; ++o) {
            const float w = W2a[(32 + c) * 32 + o];
            h1[0][o] += a * w;
            h1[1][o] += b * w;
        }
    }
#pragma unroll
    for (int o = 0; o < 32; ++o) {
        h1[0][o] = fmaxf(h1[0][o], 0.f);
        h1[1][o] = fmaxf(h1[1][o], 0.f);
    }

#pragma unroll 1
    for (int ob = 0; ob < 4; ++ob) {
        float a0[8], a1[8];
#pragma unroll
        for (int u = 0; u < 8; ++u) { const float b = b2b[ob * 8 + u]; a0[u] = b; a1[u] = b; }
#pragma unroll
        for (int hh = 0; hh < 32; ++hh) {
            const float h0v = h1[0][hh], h1v = h1[1][hh];
#pragma unroll
            for (int u = 0; u < 8; ++u) {
                const float w = W2b[hh * 32 + ob * 8 + u];
                a0[u] += h0v * w;
                a1[u] += h1v * w;
            }
        }
#pragma unroll
        for (int u = 0; u < 8; ++u) {
            float v = fmaxf(a0[u], a1[u]);
            v = fmaxf(v, __shfl_xor(v, 1));
            v = fmaxf(v, __shfl_xor(v, 2));
            v = fmaxf(v, __shfl_xor(v, 4));
            if (sub == 0) h2[(size_t)node * 32 + ob * 8 + u] = fmaxf(v, 0.f);
        }
    }
}

// ---------------------------------------------------------------------------
// K5: per-cloud global max pool (2048 x 32, tree-reduced) + Linear(32,40).
// ---------------------------------------------------------------------------
__global__ __launch_bounds__(256) void pool_fc(const float* __restrict__ h2,
                                               const float* __restrict__ Wc,
                                               const float* __restrict__ bc,
                                               float* __restrict__ out) {
    const int b = blockIdx.x;
    const int tid = threadIdx.x;
    float pm[32];
#pragma unroll
    for (int o = 0; o < 32; ++o) pm[o] = -INFINITY;
    for (int s = 0; s < 8; ++s) {
        const int node = b * 2048 + s * 256 + tid;
        const float4* row = (const float4*)(h2 + (size_t)node * 32);
#pragma unroll
        for (int q = 0; q < 8; ++q) {
            const float4 v = row[q];
            pm[q * 4 + 0] = fmaxf(pm[q * 4 + 0], v.x);
            pm[q * 4 + 1] = fmaxf(pm[q * 4 + 1], v.y);
            pm[q * 4 + 2] = fmaxf(pm[q * 4 + 2], v.z);
            pm[q * 4 + 3] = fmaxf(pm[q * 4 + 3], v.w);
        }
    }
    __shared__ float red[256][33];
    __shared__ float red2[8][33];
    __shared__ float pooled[32];
#pragma unroll
    for (int o = 0; o < 32; ++o) red[tid][o] = pm[o];
    __syncthreads();
    {
        const int oc = tid & 31, ch = tid >> 5;   // 8 chunks x 32 channels
        float m = -INFINITY;
#pragma unroll
        for (int r = 0; r < 32; ++r) m = fmaxf(m, red[ch * 32 + r][oc]);
        red2[ch][oc] = m;
    }
    __syncthreads();
    if (tid < 32) {
        float m = red2[0][tid];
#pragma unroll
        for (int c = 1; c < 8; ++c) m = fmaxf(m, red2[c][tid]);
        pooled[tid] = m;
    }
    __syncthreads();
    if (tid < 40) {
        float acc = bc[tid];
#pragma unroll
        for (int o = 0; o < 32; ++o) acc += pooled[o] * Wc[o * 40 + tid];
        out[b * 40 + tid] = acc;
    }
}

// ---------------------------------------------------------------------------
extern "C" void kernel_launch(void* const* d_in, const int* in_sizes, int n_in,
                              void* d_out, int out_size, void* d_ws, size_t ws_size,
                              hipStream_t stream) {
    const float* pos = (const float*)d_in[0];
    const float* nrm = (const float*)d_in[1];
    const float* W1a = (const float*)d_in[3];
    const float* b1a = (const float*)d_in[4];
    const float* W1b = (const float*)d_in[5];
    const float* b1b = (const float*)d_in[6];
    const float* W2a = (const float*)d_in[7];
    const float* b2a = (const float*)d_in[8];
    const float* W2b = (const float*)d_in[9];
    const float* b2b = (const float*)d_in[10];
    const float* Wc  = (const float*)d_in[11];
    const float* bc  = (const float*)d_in[12];
    float* out = (float*)d_out;

    char* ws = (char*)d_ws;
    int*   nbr = (int*)(ws + OFF_NBR);
    float* ppf = (float*)(ws + OFF_PPF);
    float* h   = (float*)(ws + OFF_H);
    float* G   = (float*)(ws + OFF_G);
    float* h2  = (float*)(ws + OFF_H2);

    hipLaunchKernelGGL(knn_ppf,      dim3(1024), dim3(256), 0, stream, pos, nrm, nbr, ppf);
    hipLaunchKernelGGL(conv1_kernel, dim3(1024), dim3(256), 0, stream, ppf, W1a, b1a, W1b, b1b, h);
    hipLaunchKernelGGL(gfromh,       dim3(128),  dim3(256), 0, stream, h, W2a, b2a, G);
    hipLaunchKernelGGL(conv2_kernel, dim3(1024), dim3(256), 0, stream, ppf, nbr, G, W2a, W2b, b2b, h2);
    hipLaunchKernelGGL(pool_fc,      dim3(16),   dim3(256), 0, stream, h2, Wc, bc, out);
}

// Round 4
// 202.822 us; speedup vs baseline: 4.1036x; 1.4849x over previous
//
#include <hip/hip_runtime.h>
#include <math.h>

// ---------------------------------------------------------------------------
// PPFNet pipeline on MI355X. B=16 clouds x 2048 pts, K=16 knn, all f32.
//  K1 knn_ppf : whole cloud in LDS; med3 top-8/slice on s=|c|^2-2p.c; wave
//               bitonic merge -> tau; rescan; exact-d2 fixup; write nbr+ppf.
//  K3 conv1   : 1 edge/thread, 16 thr/node. MLP(4->32)->relu->(32->32) in
//               4x8-output chunks (acc[8] live), 16-lane shfl-max, relu.
//  K4a gfromh : G = h @ W2a[0:32] + b2a (hoists conv2 layer1 out of edges)
//  K4b conv2  : 1 edge/thread: relu(G[j] + ppf@W2a[32:36]) -> 32x32 chunks
//  K5a pool1  : 128 blocks; per-block 256-node max reduce; int atomicMax
//               (valid: h2>=0, IEEE positive floats are int-order-preserving;
//                ws poison 0xAA = negative int = identity for the max)
//  K5b fc     : per-cloud Linear(32,40) from pooled
// ---------------------------------------------------------------------------

#define NPER 2048
#define NCLOUD 16

// ws layout (bytes)
#define OFF_NBR  (size_t)(0u)          // int   [N][16]   (2 MB)
#define OFF_PPF  (size_t)(2u << 20)    // float [N][16][4](8 MB)
#define OFF_H    (size_t)(10u << 20)   // float [N][32]   (4 MB)
#define OFF_G    (size_t)(14u << 20)   // float [N][32]   (4 MB)
#define OFF_H2   (size_t)(18u << 20)   // float [N][32]   (4 MB)
#define OFF_POOL (size_t)(22u << 20)   // int   [16][32]  (2 KB) -> ~22 MB

__device__ __forceinline__ float med3(float a, float b, float c) {
    return __builtin_amdgcn_fmed3f(a, b, c);
}
__device__ __forceinline__ void cex(float& a, float& b) {
    const float lo = fminf(a, b), hi = fmaxf(a, b); a = lo; b = hi;
}
// Sort a bitonic 16-sequence ascending (4-stage bitonic merge network).
__device__ __forceinline__ void bmerge16(float (&v)[16]) {
#pragma unroll
    for (int i = 0; i < 8; ++i) cex(v[i], v[i + 8]);
#pragma unroll
    for (int b = 0; b < 16; b += 8)
#pragma unroll
        for (int i = 0; i < 4; ++i) cex(v[b + i], v[b + i + 4]);
#pragma unroll
    for (int b = 0; b < 16; b += 4)
#pragma unroll
        for (int i = 0; i < 2; ++i) cex(v[b + i], v[b + i + 2]);
#pragma unroll
    for (int b = 0; b < 16; b += 2) cex(v[b], v[b + 1]);
}

__device__ __forceinline__ float angf(float ax, float ay, float az,
                                      float bx, float by, float bz) {
    const float cx = ay * bz - az * by;
    const float cy = az * bx - ax * bz;
    const float cz = ax * by - ay * bx;
    const float cn = sqrtf(cx * cx + cy * cy + cz * cz);
    const float dt = ax * bx + ay * by + az * bz;
    return atan2f(cn, dt);
}

// ---------------------------------------------------------------------------
// K1: knn + ppf. Block = 256 threads = 32 points x 8 slices. Grid = 1024.
// ---------------------------------------------------------------------------
__global__ __launch_bounds__(256) void knn_ppf(const float* __restrict__ pos,
                                               const float* __restrict__ nrm,
                                               int* __restrict__ nbr,
                                               float* __restrict__ ppf) {
    const int tid = threadIdx.x;
    const int pl  = tid >> 3;               // point within block (0..31)
    const int sl  = tid & 7;                // slice (0..7)
    const int gp  = blockIdx.x * 32 + pl;   // global point
    const int cloud = gp >> 11;
    const int lp  = gp & 2047;              // local point idx in cloud
    const int cbase = cloud * NPER;

    __shared__ float4 tile[2048];           // x,y,z,|c|^2  (32 KB)
    __shared__ int    hiL[32][40];          // hit local indices (5 KB)
    __shared__ int    cnt[32];

    if (tid < 32) cnt[tid] = 0;

#pragma unroll
    for (int c = 0; c < 8; ++c) {
        const int idx = c * 256 + tid;
        const float x = pos[(cbase + idx) * 3 + 0];
        const float y = pos[(cbase + idx) * 3 + 1];
        const float z = pos[(cbase + idx) * 3 + 2];
        tile[idx] = make_float4(x, y, z, x * x + y * y + z * z);
    }
    __syncthreads();

    const float4 P  = tile[lp];
    const float pn2 = P.w;
    const float m2x = -2.f * P.x, m2y = -2.f * P.y, m2z = -2.f * P.z;

    // ---- Phase A: top-8 of s per slice, branchless med3 ----
    float dl[8];
#pragma unroll
    for (int m = 0; m < 8; ++m) dl[m] = INFINITY;

#pragma unroll 4
    for (int jj = 0; jj < 256; ++jj) {
        const int cand = jj * 8 + sl;
        const float4 C = tile[cand];
        float s = fmaf(m2x, C.x, fmaf(m2y, C.y, fmaf(m2z, C.z, C.w)));
        s = (cand == lp) ? INFINITY : s;
#pragma unroll
        for (int m = 7; m >= 1; --m) dl[m] = med3(dl[m - 1], dl[m], s);
        dl[0] = fminf(dl[0], s);
    }

    // ---- Phase B: in-wave bitonic merge of the point's 8 slice lists ----
    float v[16];
#pragma unroll
    for (int i = 0; i < 8; ++i) v[i] = dl[i];
#pragma unroll
    for (int i = 0; i < 8; ++i) v[15 - i] = __shfl_xor(dl[i], 1);
    bmerge16(v);
    {
        float p[16];
#pragma unroll
        for (int i = 0; i < 16; ++i) p[i] = __shfl_xor(v[i], 2);
        float w[16];
#pragma unroll
        for (int i = 0; i < 16; ++i) w[i] = fminf(v[i], p[15 - i]);
        bmerge16(w);
#pragma unroll
        for (int i = 0; i < 16; ++i) v[i] = w[i];
    }
    float tau_s;
    {
        float p[16];
#pragma unroll
        for (int i = 0; i < 16; ++i) p[i] = __shfl_xor(v[i], 4);
        float t = -INFINITY;
#pragma unroll
        for (int i = 0; i < 16; ++i) t = fmaxf(t, fminf(v[i], p[15 - i]));
        tau_s = t;
    }
    const float tsw = tau_s + 6e-5f * (1.f + pn2 + fabsf(tau_s + pn2));

    // ---- Phase C: rescan on s, collect hit indices ----
#pragma unroll 4
    for (int jj = 0; jj < 256; ++jj) {
        const int cand = jj * 8 + sl;
        const float4 C = tile[cand];
        const float s = fmaf(m2x, C.x, fmaf(m2y, C.y, fmaf(m2z, C.z, C.w)));
        if (s <= tsw && cand != lp) {
            const int k = atomicAdd(&cnt[pl], 1);
            if (k < 40) hiL[pl][k] = cand;
        }
    }
    __syncthreads();

    // ---- Phase D: exact top-16 (bit-identical d2, index tiebreak) ----
    if (tid < 32) {
        int n = cnt[tid];
        n = n > 40 ? 40 : n;
        if (n != 16) {
            const int myl = (blockIdx.x * 32 + tid) & 2047;
            const float4 Q = tile[myl];
            unsigned long long keys[16];
#pragma unroll
            for (int m = 0; m < 16; ++m) keys[m] = ~0ULL;
            for (int i = 0; i < n; ++i) {
                const int cand = hiL[tid][i];
                const float4 C = tile[cand];
                const float dx = __fsub_rn(Q.x, C.x);
                const float dy = __fsub_rn(Q.y, C.y);
                const float dz = __fsub_rn(Q.z, C.z);
                const float d2 = __fadd_rn(__fadd_rn(__fmul_rn(dx, dx),
                                                     __fmul_rn(dy, dy)),
                                           __fmul_rn(dz, dz));
                const unsigned long long key =
                    ((unsigned long long)__float_as_uint(d2) << 32) |
                    (unsigned int)cand;
                if (key < keys[15]) {
#pragma unroll
                    for (int m = 15; m >= 1; --m) {
                        const bool up   = key < keys[m - 1];
                        const bool here = key < keys[m];
                        keys[m] = up ? keys[m - 1] : (here ? key : keys[m]);
                    }
                    if (key < keys[0]) keys[0] = key;
                }
            }
#pragma unroll
            for (int m = 0; m < 16; ++m)
                hiL[tid][m] = (int)(unsigned int)(keys[m] & 0xFFFFFFFFu);
        }
    }
    __syncthreads();

    // ---- Phase E: nbr + ppf (2 edges per thread) ----
    const float nix = nrm[gp * 3 + 0], niy = nrm[gp * 3 + 1], niz = nrm[gp * 3 + 2];
    const float px = P.x, py = P.y, pz = P.z;
#pragma unroll
    for (int e = 0; e < 2; ++e) {
        const int m = sl * 2 + e;
        const int j = cbase + hiL[pl][m];
        nbr[gp * 16 + m] = j;
        const float pjx = pos[j * 3 + 0], pjy = pos[j * 3 + 1], pjz = pos[j * 3 + 2];
        const float njx = nrm[j * 3 + 0], njy = nrm[j * 3 + 1], njz = nrm[j * 3 + 2];
        const float dx = pjx - px, dy = pjy - py, dz = pjz - pz;
        float4 o;
        o.x = sqrtf(dx * dx + dy * dy + dz * dz);
        o.y = angf(nix, niy, niz, dx, dy, dz);
        o.z = angf(njx, njy, njz, dx, dy, dz);
        o.w = angf(nix, niy, niz, njx, njy, njz);
        ((float4*)ppf)[(size_t)gp * 16 + m] = o;
    }
}

// ---------------------------------------------------------------------------
// K3: conv1. 1 edge/thread, 16 threads/node. Grid 2048 x 256.
// ---------------------------------------------------------------------------
__global__ __launch_bounds__(256, 4) void conv1_kernel(const float* __restrict__ ppf,
                                                       const float* __restrict__ W1a,
                                                       const float* __restrict__ b1a,
                                                       const float* __restrict__ W1b,
                                                       const float* __restrict__ b1b,
                                                       float* __restrict__ h) {
    const int gid    = blockIdx.x * 256 + threadIdx.x;   // edge id
    const int node   = gid >> 4;
    const int lane16 = threadIdx.x & 15;

    const float4 x = ((const float4*)ppf)[gid];

    float h1[32];
#pragma unroll
    for (int o = 0; o < 32; ++o) {
        h1[o] = fmaxf(fmaf(x.x, W1a[o],
                     fmaf(x.y, W1a[32 + o],
                     fmaf(x.z, W1a[64 + o],
                     fmaf(x.w, W1a[96 + o], b1a[o])))), 0.f);
    }

#pragma unroll 1
    for (int ob = 0; ob < 4; ++ob) {
        float acc[8];
#pragma unroll
        for (int u = 0; u < 8; ++u) acc[u] = b1b[ob * 8 + u];
#pragma unroll
        for (int hh = 0; hh < 32; ++hh) {
            const float hv = h1[hh];
#pragma unroll
            for (int u = 0; u < 8; ++u)
                acc[u] = fmaf(hv, W1b[hh * 32 + ob * 8 + u], acc[u]);
        }
#pragma unroll
        for (int u = 0; u < 8; ++u) {
            float v = acc[u];
            v = fmaxf(v, __shfl_xor(v, 1));
            v = fmaxf(v, __shfl_xor(v, 2));
            v = fmaxf(v, __shfl_xor(v, 4));
            v = fmaxf(v, __shfl_xor(v, 8));
            acc[u] = fmaxf(v, 0.f);
        }
        if (lane16 == 0) {
            float4* dst = (float4*)(h + (size_t)node * 32 + ob * 8);
            dst[0] = make_float4(acc[0], acc[1], acc[2], acc[3]);
            dst[1] = make_float4(acc[4], acc[5], acc[6], acc[7]);
        }
    }
}

// ---------------------------------------------------------------------------
// K4a: G = h @ W2a[0:32,:] + b2a  (per node)
// ---------------------------------------------------------------------------
__global__ __launch_bounds__(256) void gfromh(const float* __restrict__ h,
                                              const float* __restrict__ W2a,
                                              const float* __restrict__ b2a,
                                              float* __restrict__ G) {
    const int n = blockIdx.x * 256 + threadIdx.x;
    float hr[32];
    const float4* row = (const float4*)(h + (size_t)n * 32);
#pragma unroll
    for (int q = 0; q < 8; ++q) {
        const float4 v = row[q];
        hr[q * 4 + 0] = v.x; hr[q * 4 + 1] = v.y; hr[q * 4 + 2] = v.z; hr[q * 4 + 3] = v.w;
    }
    float acc[32];
#pragma unroll
    for (int o = 0; o < 32; ++o) acc[o] = b2a[o];
#pragma unroll
    for (int c = 0; c < 32; ++c) {
        const float hv = hr[c];
#pragma unroll
        for (int o = 0; o < 32; ++o) acc[o] = fmaf(hv, W2a[c * 32 + o], acc[o]);
    }
    float4* go = (float4*)(G + (size_t)n * 32);
#pragma unroll
    for (int q = 0; q < 8; ++q)
        go[q] = make_float4(acc[q * 4 + 0], acc[q * 4 + 1], acc[q * 4 + 2], acc[q * 4 + 3]);
}

// ---------------------------------------------------------------------------
// K4b: conv2. 1 edge/thread, 16 threads/node. Grid 2048 x 256.
// ---------------------------------------------------------------------------
__global__ __launch_bounds__(256, 4) void conv2_kernel(const float* __restrict__ ppf,
                                                       const int* __restrict__ nbr,
                                                       const float* __restrict__ G,
                                                       const float* __restrict__ W2a,
                                                       const float* __restrict__ W2b,
                                                       const float* __restrict__ b2b,
                                                       float* __restrict__ h2) {
    const int gid    = blockIdx.x * 256 + threadIdx.x;   // edge id
    const int node   = gid >> 4;
    const int lane16 = threadIdx.x & 15;

    const int j = nbr[gid];

    float h1[32];
    {
        const float4* gr = (const float4*)(G + (size_t)j * 32);
#pragma unroll
        for (int q = 0; q < 8; ++q) {
            const float4 v = gr[q];
            h1[q * 4 + 0] = v.x; h1[q * 4 + 1] = v.y;
            h1[q * 4 + 2] = v.z; h1[q * 4 + 3] = v.w;
        }
    }
    const float4 x = ((const float4*)ppf)[gid];
#pragma unroll
    for (int o = 0; o < 32; ++o) {
        h1[o] = fmaxf(fmaf(x.x, W2a[32 * 32 + o],
                     fmaf(x.y, W2a[33 * 32 + o],
                     fmaf(x.z, W2a[34 * 32 + o],
                     fmaf(x.w, W2a[35 * 32 + o], h1[o])))), 0.f);
    }

#pragma unroll 1
    for (int ob = 0; ob < 4; ++ob) {
        float acc[8];
#pragma unroll
        for (int u = 0; u < 8; ++u) acc[u] = b2b[ob * 8 + u];
#pragma unroll
        for (int hh = 0; hh < 32; ++hh) {
            const float hv = h1[hh];
#pragma unroll
            for (int u = 0; u < 8; ++u)
                acc[u] = fmaf(hv, W2b[hh * 32 + ob * 8 + u], acc[u]);
        }
#pragma unroll
        for (int u = 0; u < 8; ++u) {
            float v = acc[u];
            v = fmaxf(v, __shfl_xor(v, 1));
            v = fmaxf(v, __shfl_xor(v, 2));
            v = fmaxf(v, __shfl_xor(v, 4));
            v = fmaxf(v, __shfl_xor(v, 8));
            acc[u] = fmaxf(v, 0.f);
        }
        if (lane16 == 0) {
            float4* dst = (float4*)(h2 + (size_t)node * 32 + ob * 8);
            dst[0] = make_float4(acc[0], acc[1], acc[2], acc[3]);
            dst[1] = make_float4(acc[4], acc[5], acc[6], acc[7]);
        }
    }
}

// ---------------------------------------------------------------------------
// K5a: pool1. Grid 128 x 256: 1 node/thread, block-reduce, int atomicMax.
// h2 >= 0 so positive-float int compare is order-preserving; 0xAA poison
// and 0x00 both act as identity.
// ---------------------------------------------------------------------------
__global__ __launch_bounds__(256) void pool1(const float* __restrict__ h2,
                                             int* __restrict__ pooledi) {
    const int tid  = threadIdx.x;
    const int node = blockIdx.x * 256 + tid;
    const int cloud = node >> 11;

    float pm[32];
    const float4* row = (const float4*)(h2 + (size_t)node * 32);
#pragma unroll
    for (int q = 0; q < 8; ++q) {
        const float4 v = row[q];
        pm[q * 4 + 0] = v.x; pm[q * 4 + 1] = v.y;
        pm[q * 4 + 2] = v.z; pm[q * 4 + 3] = v.w;
    }

    __shared__ float red[256][33];
    __shared__ float red2[8][33];
#pragma unroll
    for (int o = 0; o < 32; ++o) red[tid][o] = pm[o];
    __syncthreads();
    {
        const int oc = tid & 31, ch = tid >> 5;
        float m = -INFINITY;
#pragma unroll
        for (int r = 0; r < 32; ++r) m = fmaxf(m, red[ch * 32 + r][oc]);
        red2[ch][oc] = m;
    }
    __syncthreads();
    if (tid < 32) {
        float m = red2[0][tid];
#pragma unroll
        for (int c = 1; c < 8; ++c) m = fmaxf(m, red2[c][tid]);
        atomicMax(&pooledi[cloud * 32 + tid], __float_as_int(m));
    }
}

// ---------------------------------------------------------------------------
// K5b: fc. Grid 16 x 64. out[b][c] = bc[c] + pooled[b] . Wc[:,c]
// ---------------------------------------------------------------------------
__global__ __launch_bounds__(64) void fc_kernel(const int* __restrict__ pooledi,
                                                const float* __restrict__ Wc,
                                                const float* __restrict__ bc,
                                                float* __restrict__ out) {
    const int b = blockIdx.x;
    const int tid = threadIdx.x;
    if (tid < 40) {
        float acc = bc[tid];
#pragma unroll
        for (int o = 0; o < 32; ++o)
            acc = fmaf(__int_as_float(pooledi[b * 32 + o]), Wc[o * 40 + tid], acc);
        out[b * 40 + tid] = acc;
    }
}

// ---------------------------------------------------------------------------
extern "C" void kernel_launch(void* const* d_in, const int* in_sizes, int n_in,
                              void* d_out, int out_size, void* d_ws, size_t ws_size,
                              hipStream_t stream) {
    const float* pos = (const float*)d_in[0];
    const float* nrm = (const float*)d_in[1];
    const float* W1a = (const float*)d_in[3];
    const float* b1a = (const float*)d_in[4];
    const float* W1b = (const float*)d_in[5];
    const float* b1b = (const float*)d_in[6];
    const float* W2a = (const float*)d_in[7];
    const float* b2a = (const float*)d_in[8];
    const float* W2b = (const float*)d_in[9];
    const float* b2b = (const float*)d_in[10];
    const float* Wc  = (const float*)d_in[11];
    const float* bc  = (const float*)d_in[12];
    float* out = (float*)d_out;

    char* ws = (char*)d_ws;
    int*   nbr = (int*)(ws + OFF_NBR);
    float* ppf = (float*)(ws + OFF_PPF);
    float* h   = (float*)(ws + OFF_H);
    float* G   = (float*)(ws + OFF_G);
    float* h2  = (float*)(ws + OFF_H2);
    int*   pli = (int*)(ws + OFF_POOL);

    hipLaunchKernelGGL(knn_ppf,      dim3(1024), dim3(256), 0, stream, pos, nrm, nbr, ppf);
    hipLaunchKernelGGL(conv1_kernel, dim3(2048), dim3(256), 0, stream, ppf, W1a, b1a, W1b, b1b, h);
    hipLaunchKernelGGL(gfromh,       dim3(128),  dim3(256), 0, stream, h, W2a, b2a, G);
    hipLaunchKernelGGL(conv2_kernel, dim3(2048), dim3(256), 0, stream, ppf, nbr, G, W2a, W2b, b2b, h2);
    hipLaunchKernelGGL(pool1,        dim3(128),  dim3(256), 0, stream, h2, pli);
    hipLaunchKernelGGL(fc_kernel,    dim3(16),   dim3(64),  0, stream, pli, Wc, bc, out);
}

// Round 5
// 193.559 us; speedup vs baseline: 4.3000x; 1.0479x over previous
//
#include <hip/hip_runtime.h>
#include <math.h>

// ---------------------------------------------------------------------------
// PPFNet pipeline on MI355X. B=16 clouds x 2048 pts, K=16 knn, all f32.
// 3 launches (was 6 - inter-launch gaps were ~85us of the round-4 total):
//  K1 knn_conv1 : block = 16 points x 16 slices; whole cloud in LDS.
//     A: med3 top-4/slice of s=|c|^2-2p.c (8 VALU/candidate)
//     B: 4-round shuffle bitonic merge of 16 sorted-4 lists -> tau (16th)
//     C: rescan, collect hits <= tau_widened
//     D: cnt!=16 points: exact d2 (bit-identical to numpy) + idx tiebreak
//     E: nbr + ppf (1 edge/thread, kept in regs)
//     then FUSED conv1 (edge-local) + gfromh (node-local via 16-lane shfl):
//     writes nbr, ppf, G. No h round-trip, no extra launches.
//  K2 conv2_pool: 1 edge/thread: relu(G[j] + ppf@W2a[32:36]) -> 32x32 ->
//     16-lane shfl max -> block pool reduce -> int atomicMax per cloud.
//     h2 never touches global memory.
//  K3 fc        : per-cloud Linear(32,40).
// ---------------------------------------------------------------------------

#define NPER 2048
#define NCLOUD 16

// ws layout (bytes)
#define OFF_NBR  (size_t)(0u)          // int   [N][16]    (2 MB)
#define OFF_PPF  (size_t)(2u << 20)    // float [N][16][4] (8 MB)
#define OFF_G    (size_t)(10u << 20)   // float [N][32]    (4 MB)
#define OFF_POOL (size_t)(14u << 20)   // int   [16][32]   (2 KB)

__device__ __forceinline__ float med3(float a, float b, float c) {
    return __builtin_amdgcn_fmed3f(a, b, c);
}
__device__ __forceinline__ void cex(float& a, float& b) {
    const float lo = fminf(a, b), hi = fmaxf(a, b); a = lo; b = hi;
}
// Sort a bitonic 8-sequence ascending.
__device__ __forceinline__ void bmerge8(float (&v)[8]) {
#pragma unroll
    for (int i = 0; i < 4; ++i) cex(v[i], v[i + 4]);
#pragma unroll
    for (int b = 0; b < 8; b += 4)
#pragma unroll
        for (int i = 0; i < 2; ++i) cex(v[b + i], v[b + i + 2]);
#pragma unroll
    for (int b = 0; b < 8; b += 2) cex(v[b], v[b + 1]);
}
// Sort a bitonic 16-sequence ascending.
__device__ __forceinline__ void bmerge16(float (&v)[16]) {
#pragma unroll
    for (int i = 0; i < 8; ++i) cex(v[i], v[i + 8]);
#pragma unroll
    for (int b = 0; b < 16; b += 8)
#pragma unroll
        for (int i = 0; i < 4; ++i) cex(v[b + i], v[b + i + 4]);
#pragma unroll
    for (int b = 0; b < 16; b += 4)
#pragma unroll
        for (int i = 0; i < 2; ++i) cex(v[b + i], v[b + i + 2]);
#pragma unroll
    for (int b = 0; b < 16; b += 2) cex(v[b], v[b + 1]);
}

__device__ __forceinline__ float angf(float ax, float ay, float az,
                                      float bx, float by, float bz) {
    const float cx = ay * bz - az * by;
    const float cy = az * bx - ax * bz;
    const float cz = ax * by - ay * bx;
    const float cn = sqrtf(cx * cx + cy * cy + cz * cz);
    const float dt = ax * bx + ay * by + az * bz;
    return atan2f(cn, dt);
}

// ---------------------------------------------------------------------------
// K1: knn + ppf + conv1 + gfromh. Block = 256 = 16 points x 16 slices.
// Grid = 2048. LDS ~35 KB -> 4 blocks/CU.
// ---------------------------------------------------------------------------
__global__ __launch_bounds__(256) void knn_conv1(const float* __restrict__ pos,
                                                 const float* __restrict__ nrm,
                                                 const float* __restrict__ W1a,
                                                 const float* __restrict__ b1a,
                                                 const float* __restrict__ W1b,
                                                 const float* __restrict__ b1b,
                                                 const float* __restrict__ W2a,
                                                 const float* __restrict__ b2a,
                                                 int* __restrict__ nbr,
                                                 float* __restrict__ ppf,
                                                 float* __restrict__ G) {
    const int tid = threadIdx.x;
    const int pl  = tid >> 4;               // point within block (0..15)
    const int sl  = tid & 15;               // slice / lane-in-node (0..15)
    const int gp  = blockIdx.x * 16 + pl;   // global point
    const int cloud = gp >> 11;
    const int lp  = gp & 2047;              // local point idx in cloud
    const int cbase = cloud * NPER;

    __shared__ float4 tile[2048];           // x,y,z,|c|^2  (32 KB)
    __shared__ int    hiL[16][40];          // hit local indices (2.5 KB)
    __shared__ int    cnt[16];

    if (tid < 16) cnt[tid] = 0;

#pragma unroll
    for (int c = 0; c < 8; ++c) {
        const int idx = c * 256 + tid;
        const float x = pos[(cbase + idx) * 3 + 0];
        const float y = pos[(cbase + idx) * 3 + 1];
        const float z = pos[(cbase + idx) * 3 + 2];
        tile[idx] = make_float4(x, y, z, x * x + y * y + z * z);
    }
    __syncthreads();

    const float4 P  = tile[lp];
    const float pn2 = P.w;
    const float m2x = -2.f * P.x, m2y = -2.f * P.y, m2z = -2.f * P.z;

    // ---- Phase A: top-4 of s per slice (128 candidates), branchless ----
    float dl[4];
#pragma unroll
    for (int m = 0; m < 4; ++m) dl[m] = INFINITY;

#pragma unroll 4
    for (int jj = 0; jj < 128; ++jj) {
        const int cand = jj * 16 + sl;
        const float4 C = tile[cand];
        float s = fmaf(m2x, C.x, fmaf(m2y, C.y, fmaf(m2z, C.z, C.w)));
        s = (cand == lp) ? INFINITY : s;
        dl[3] = med3(dl[2], dl[3], s);
        dl[2] = med3(dl[1], dl[2], s);
        dl[1] = med3(dl[0], dl[1], s);
        dl[0] = fminf(dl[0], s);
    }

    // ---- Phase B: shuffle bitonic merge of 16 sorted-4 lists -> tau ----
    float tau_s;
    {
        // xor 1: sorted-4 + reversed partner -> bitonic-8 -> sorted-8
        float v8[8];
#pragma unroll
        for (int i = 0; i < 4; ++i) v8[i] = dl[i];
#pragma unroll
        for (int i = 0; i < 4; ++i) v8[7 - i] = __shfl_xor(dl[i], 1);
        bmerge8(v8);
        // xor 2: sorted-8 + reversed partner -> bitonic-16 -> sorted-16
        float v[16];
#pragma unroll
        for (int i = 0; i < 8; ++i) v[i] = v8[i];
#pragma unroll
        for (int i = 0; i < 8; ++i) v[15 - i] = __shfl_xor(v8[i], 2);
        bmerge16(v);
        // xor 4: keep lowest 16 of 32, re-sort
        {
            float p[16];
#pragma unroll
            for (int i = 0; i < 16; ++i) p[i] = __shfl_xor(v[i], 4);
            float w[16];
#pragma unroll
            for (int i = 0; i < 16; ++i) w[i] = fminf(v[i], p[15 - i]);
            bmerge16(w);
#pragma unroll
            for (int i = 0; i < 16; ++i) v[i] = w[i];
        }
        // xor 8: tau = max of the lowest-16 multiset of the 64-union
        {
            float p[16];
#pragma unroll
            for (int i = 0; i < 16; ++i) p[i] = __shfl_xor(v[i], 8);
            float t = -INFINITY;
#pragma unroll
            for (int i = 0; i < 16; ++i) t = fmaxf(t, fminf(v[i], p[15 - i]));
            tau_s = t;
        }
    }
    const float tsw = tau_s + 6e-5f * (1.f + pn2 + fabsf(tau_s + pn2));

    // ---- Phase C: rescan on s, collect hit indices ----
#pragma unroll 4
    for (int jj = 0; jj < 128; ++jj) {
        const int cand = jj * 16 + sl;
        const float4 C = tile[cand];
        const float s = fmaf(m2x, C.x, fmaf(m2y, C.y, fmaf(m2z, C.z, C.w)));
        if (s <= tsw && cand != lp) {
            const int k = atomicAdd(&cnt[pl], 1);
            if (k < 40) hiL[pl][k] = cand;
        }
    }
    __syncthreads();

    // ---- Phase D: exact top-16 (bit-identical d2, index tiebreak) ----
    if (tid < 16) {
        int n = cnt[tid];
        n = n > 40 ? 40 : n;
        if (n != 16) {
            const int myl = (blockIdx.x * 16 + tid) & 2047;
            const float4 Q = tile[myl];
            unsigned long long keys[16];
#pragma unroll
            for (int m = 0; m < 16; ++m) keys[m] = ~0ULL;
            for (int i = 0; i < n; ++i) {
                const int cand = hiL[tid][i];
                const float4 C = tile[cand];
                const float dx = __fsub_rn(Q.x, C.x);
                const float dy = __fsub_rn(Q.y, C.y);
                const float dz = __fsub_rn(Q.z, C.z);
                const float d2 = __fadd_rn(__fadd_rn(__fmul_rn(dx, dx),
                                                     __fmul_rn(dy, dy)),
                                           __fmul_rn(dz, dz));
                const unsigned long long key =
                    ((unsigned long long)__float_as_uint(d2) << 32) |
                    (unsigned int)cand;
                if (key < keys[15]) {
#pragma unroll
                    for (int m = 15; m >= 1; --m) {
                        const bool up   = key < keys[m - 1];
                        const bool here = key < keys[m];
                        keys[m] = up ? keys[m - 1] : (here ? key : keys[m]);
                    }
                    if (key < keys[0]) keys[0] = key;
                }
            }
#pragma unroll
            for (int m = 0; m < 16; ++m)
                hiL[tid][m] = (int)(unsigned int)(keys[m] & 0xFFFFFFFFu);
        }
    }
    __syncthreads();

    // ---- Phase E: nbr + ppf (1 edge per thread, ppf kept in regs) ----
    const float nix = nrm[gp * 3 + 0], niy = nrm[gp * 3 + 1], niz = nrm[gp * 3 + 2];
    float4 x;
    {
        const int jl = hiL[pl][sl];
        const int j  = cbase + jl;
        nbr[gp * 16 + sl] = j;
        const float4 C = tile[jl];
        const float njx = nrm[j * 3 + 0], njy = nrm[j * 3 + 1], njz = nrm[j * 3 + 2];
        const float dx = C.x - P.x, dy = C.y - P.y, dz = C.z - P.z;
        x.x = sqrtf(dx * dx + dy * dy + dz * dz);
        x.y = angf(nix, niy, niz, dx, dy, dz);
        x.z = angf(njx, njy, njz, dx, dy, dz);
        x.w = angf(nix, niy, niz, njx, njy, njz);
        ((float4*)ppf)[(size_t)gp * 16 + sl] = x;
    }

    // ---- FUSED conv1: layer1 (4->32) on this edge ----
    float h1[32];
#pragma unroll
    for (int o = 0; o < 32; ++o) {
        h1[o] = fmaxf(fmaf(x.x, W1a[o],
                     fmaf(x.y, W1a[32 + o],
                     fmaf(x.z, W1a[64 + o],
                     fmaf(x.w, W1a[96 + o], b1a[o])))), 0.f);
    }

    // ---- layer2 (32->32) in 4x8 chunks + 16-lane max; all lanes keep h ----
    float hr[32];
#pragma unroll 1
    for (int ob = 0; ob < 4; ++ob) {
        float acc[8];
#pragma unroll
        for (int u = 0; u < 8; ++u) acc[u] = b1b[ob * 8 + u];
#pragma unroll
        for (int hh = 0; hh < 32; ++hh) {
            const float hv = h1[hh];
#pragma unroll
            for (int u = 0; u < 8; ++u)
                acc[u] = fmaf(hv, W1b[hh * 32 + ob * 8 + u], acc[u]);
        }
#pragma unroll
        for (int u = 0; u < 8; ++u) {
            float v = acc[u];
            v = fmaxf(v, __shfl_xor(v, 1));
            v = fmaxf(v, __shfl_xor(v, 2));
            v = fmaxf(v, __shfl_xor(v, 4));
            v = fmaxf(v, __shfl_xor(v, 8));
            hr[ob * 8 + u] = fmaxf(v, 0.f);
        }
    }

    // ---- FUSED gfromh: G[node] = hr @ W2a[0:32,:] + b2a (2 cols/lane) ----
    {
        const int c0 = sl * 2;
        float g0 = b2a[c0], g1 = b2a[c0 + 1];
#pragma unroll
        for (int k = 0; k < 32; ++k) {
            g0 = fmaf(hr[k], W2a[k * 32 + c0], g0);
            g1 = fmaf(hr[k], W2a[k * 32 + c0 + 1], g1);
        }
        ((float2*)(G + (size_t)gp * 32))[sl] = make_float2(g0, g1);
    }
}

// ---------------------------------------------------------------------------
// K2: conv2 + pool. 1 edge/thread, 16 threads/node, block = 16 nodes.
// Grid 2048 x 256. h2 never hits global; block-reduced then atomicMax.
// pooledi poison 0xAA.. is a negative int = identity (h2 >= 0).
// ---------------------------------------------------------------------------
__global__ __launch_bounds__(256, 4) void conv2_pool(const float* __restrict__ ppf,
                                                     const int* __restrict__ nbr,
                                                     const float* __restrict__ G,
                                                     const float* __restrict__ W2a,
                                                     const float* __restrict__ W2b,
                                                     const float* __restrict__ b2b,
                                                     int* __restrict__ pooledi) {
    const int tid    = threadIdx.x;
    const int gid    = blockIdx.x * 256 + tid;    // edge id
    const int node16 = tid >> 4;                  // node within block
    const int cloud  = blockIdx.x >> 7;           // 128 blocks per cloud

    const int j = nbr[gid];

    float h1[32];
    {
        const float4* gr = (const float4*)(G + (size_t)j * 32);
#pragma unroll
        for (int q = 0; q < 8; ++q) {
            const float4 v = gr[q];
            h1[q * 4 + 0] = v.x; h1[q * 4 + 1] = v.y;
            h1[q * 4 + 2] = v.z; h1[q * 4 + 3] = v.w;
        }
    }
    const float4 x = ((const float4*)ppf)[gid];
#pragma unroll
    for (int o = 0; o < 32; ++o) {
        h1[o] = fmaxf(fmaf(x.x, W2a[32 * 32 + o],
                     fmaf(x.y, W2a[33 * 32 + o],
                     fmaf(x.z, W2a[34 * 32 + o],
                     fmaf(x.w, W2a[35 * 32 + o], h1[o])))), 0.f);
    }

    float h2r[32];
#pragma unroll 1
    for (int ob = 0; ob < 4; ++ob) {
        float acc[8];
#pragma unroll
        for (int u = 0; u < 8; ++u) acc[u] = b2b[ob * 8 + u];
#pragma unroll
        for (int hh = 0; hh < 32; ++hh) {
            const float hv = h1[hh];
#pragma unroll
            for (int u = 0; u < 8; ++u)
                acc[u] = fmaf(hv, W2b[hh * 32 + ob * 8 + u], acc[u]);
        }
#pragma unroll
        for (int u = 0; u < 8; ++u) {
            float v = acc[u];
            v = fmaxf(v, __shfl_xor(v, 1));
            v = fmaxf(v, __shfl_xor(v, 2));
            v = fmaxf(v, __shfl_xor(v, 4));
            v = fmaxf(v, __shfl_xor(v, 8));
            h2r[ob * 8 + u] = fmaxf(v, 0.f);
        }
    }

    // ---- block pool: 16 nodes -> 32 channels -> atomicMax per cloud ----
    __shared__ float sh[16][33];
    if ((tid & 15) == 0) {
#pragma unroll
        for (int o = 0; o < 32; ++o) sh[node16][o] = h2r[o];
    }
    __syncthreads();
    if (tid < 32) {
        float m = sh[0][tid];
#pragma unroll
        for (int n = 1; n < 16; ++n) m = fmaxf(m, sh[n][tid]);
        atomicMax(&pooledi[cloud * 32 + tid], __float_as_int(m));
    }
}

// ---------------------------------------------------------------------------
// K3: fc. Grid 16 x 64. out[b][c] = bc[c] + pooled[b] . Wc[:,c]
// ---------------------------------------------------------------------------
__global__ __launch_bounds__(64) void fc_kernel(const int* __restrict__ pooledi,
                                                const float* __restrict__ Wc,
                                                const float* __restrict__ bc,
                                                float* __restrict__ out) {
    const int b = blockIdx.x;
    const int tid = threadIdx.x;
    if (tid < 40) {
        float acc = bc[tid];
#pragma unroll
        for (int o = 0; o < 32; ++o)
            acc = fmaf(__int_as_float(pooledi[b * 32 + o]), Wc[o * 40 + tid], acc);
        out[b * 40 + tid] = acc;
    }
}

// ---------------------------------------------------------------------------
extern "C" void kernel_launch(void* const* d_in, const int* in_sizes, int n_in,
                              void* d_out, int out_size, void* d_ws, size_t ws_size,
                              hipStream_t stream) {
    const float* pos = (const float*)d_in[0];
    const float* nrm = (const float*)d_in[1];
    const float* W1a = (const float*)d_in[3];
    const float* b1a = (const float*)d_in[4];
    const float* W1b = (const float*)d_in[5];
    const float* b1b = (const float*)d_in[6];
    const float* W2a = (const float*)d_in[7];
    const float* b2a = (const float*)d_in[8];
    const float* W2b = (const float*)d_in[9];
    const float* b2b = (const float*)d_in[10];
    const float* Wc  = (const float*)d_in[11];
    const float* bc  = (const float*)d_in[12];
    float* out = (float*)d_out;

    char* ws = (char*)d_ws;
    int*   nbr = (int*)(ws + OFF_NBR);
    float* ppf = (float*)(ws + OFF_PPF);
    float* G   = (float*)(ws + OFF_G);
    int*   pli = (int*)(ws + OFF_POOL);

    hipLaunchKernelGGL(knn_conv1,  dim3(2048), dim3(256), 0, stream,
                       pos, nrm, W1a, b1a, W1b, b1b, W2a, b2a, nbr, ppf, G);
    hipLaunchKernelGGL(conv2_pool, dim3(2048), dim3(256), 0, stream,
                       ppf, nbr, G, W2a, W2b, b2b, pli);
    hipLaunchKernelGGL(fc_kernel,  dim3(16),   dim3(64),  0, stream,
                       pli, Wc, bc, out);
}